// Round 13
// baseline (768.375 us; speedup 1.0000x reference)
//
#include <hip/hip_runtime.h>
#include <stdint.h>

// reference: rec_audio (256, 131072) f32, k = int(0.03*131072) = 3932
#define NROWS 256
#define NCOLS 131072
#define KSEL  3932
#define TPB   1024
#define HALF  (NCOLS / 2)            // 65536 elems per pass-1 block
#define H_ITERS (HALF / (TPB * 4))   // 16 float4-iterations per thread
// Candidate threshold on m = bits>>9 (23-bit). p = (2^23-TM)/2^23 = 0.033582
// -> mean candidates/row = 4401, sigma = 65. KSEL=3932 is 7.2 sigma below,
// MAXC=5120 is 11 sigma above. Deterministic stream -> if it passes once, always.
#define TM    8106908u
#define TB    (TM << 9)              // 4150736896u: bits >= TB  <=>  (bits>>9) >= TM
#define MAXC  5120
#define SBINS 256                    // selection histogram: bin = (m-TM)>>11, max bin 137
#define MAXB  256                    // boundary-bin capacity (mean ~32)

// single-instruction rotate: rotl(v,r) == v_alignbit_b32(v, v, 32-r)
__device__ __forceinline__ uint32_t rotl32(uint32_t v, int r) {
    return __builtin_amdgcn_alignbit(v, v, 32 - r);
}

// JAX threefry2x32, key (0, 42), partitionable scheme:
// counter = (uint64)j -> x0 = 0, x1 = j; bits = out0 ^ out1.  (verified bit-exact, round 1)
__device__ __forceinline__ uint32_t jax_bits(uint32_t j) {
    const uint32_t ks0 = 0u;
    const uint32_t ks1 = 42u;
    const uint32_t ks2 = ks0 ^ ks1 ^ 0x1BD11BDAu;
    uint32_t x0 = 0u + ks0;
    uint32_t x1 = j + ks1;
#define TF_RND(r) { x0 += x1; x1 = rotl32(x1, r); x1 ^= x0; }
    TF_RND(13) TF_RND(15) TF_RND(26) TF_RND(6)
    x0 += ks1; x1 += ks2 + 1u;
    TF_RND(17) TF_RND(29) TF_RND(16) TF_RND(24)
    x0 += ks2; x1 += ks0 + 2u;
    TF_RND(13) TF_RND(15) TF_RND(26) TF_RND(6)
    x0 += ks0; x1 += ks1 + 3u;
    TF_RND(17) TF_RND(29) TF_RND(16) TF_RND(24)
    x0 += ks1; x1 += ks2 + 4u;
    TF_RND(13) TF_RND(15) TF_RND(26) TF_RND(6)
    x0 += ks2; x1 += ks0 + 5u;
#undef TF_RND
    return x0 ^ x1;
}

// d_ws layout: [0..255] per-row candidate counts; then per-row index lists.
__global__ void zero_counts(uint32_t* __restrict__ cnt) {
    cnt[threadIdx.x] = 0u;
}

// Pass 1: 512 blocks (2 per row) -> 2 blocks/CU = 32 waves/CU (100% occupancy).
// No LDS. threefry + fused copy + global candidate-index push.
__global__ __launch_bounds__(TPB, 8) void pass1_kernel(const float* __restrict__ in,
                                                       float* __restrict__ out,
                                                       uint32_t* __restrict__ cnt,
                                                       uint32_t* __restrict__ cidx_g) {
    const uint32_t bid  = blockIdx.x;
    const uint32_t row  = bid >> 1;
    const uint32_t half = bid & 1u;
    const uint32_t tid  = threadIdx.x;
    const uint32_t hbase = row * (uint32_t)NCOLS + half * (uint32_t)HALF;

    const float4* in4  = (const float4*)(in + hbase);
    float4*       out4 = (float4*)(out + hbase);
    uint32_t* myidx = cidx_g + row * (uint32_t)MAXC;
    uint32_t* mycnt = cnt + row;
    const uint32_t colbase = half * (uint32_t)HALF;

    for (int it = 0; it < H_ITERS; ++it) {
        uint32_t vi = (uint32_t)it * TPB + tid;
        uint32_t c  = vi * 4u;              // local column within half
        uint32_t j  = hbase + c;
        float4 v = in4[vi];                 // issue load early; latency hides under threefry
        uint32_t b0 = jax_bits(j + 0u);
        uint32_t b1 = jax_bits(j + 1u);
        uint32_t b2 = jax_bits(j + 2u);
        uint32_t b3 = jax_bits(j + 3u);
        out4[vi] = v;                       // provisional passthrough copy
        if (b0 >= TB) { uint32_t p = atomicAdd(mycnt, 1u); if (p < MAXC) myidx[p] = colbase + c + 0u; }
        if (b1 >= TB) { uint32_t p = atomicAdd(mycnt, 1u); if (p < MAXC) myidx[p] = colbase + c + 1u; }
        if (b2 >= TB) { uint32_t p = atomicAdd(mycnt, 1u); if (p < MAXC) myidx[p] = colbase + c + 2u; }
        if (b3 >= TB) { uint32_t p = atomicAdd(mycnt, 1u); if (p < MAXC) myidx[p] = colbase + c + 3u; }
    }
}

// Pass 2: 256 blocks (1 per row). Recompute m for ~4400 candidates, select
// exact top-k boundary (XLA stable tie-break), scatter zeros.
__global__ __launch_bounds__(TPB) void select_kernel(float* __restrict__ out,
                                                     const uint32_t* __restrict__ cnt,
                                                     const uint32_t* __restrict__ cidx_g) {
    __shared__ uint32_t cm[MAXC];     // 20 KB: candidate m - TM (19 bits)
    __shared__ uint32_t cidx[MAXC];   // 20 KB: candidate column index
    __shared__ uint32_t hist[SBINS];  // 1 KB
    __shared__ uint32_t scanb[SBINS]; // 1 KB
    __shared__ uint32_t bkeys[MAXB];  // 1 KB
    __shared__ uint32_t s_bcnt;
    __shared__ uint32_t s_bstar;
    __shared__ uint32_t s_r;
    __shared__ uint32_t s_tkey;

    const uint32_t row  = blockIdx.x;
    const uint32_t tid  = threadIdx.x;
    const uint32_t base = row * (uint32_t)NCOLS;

    if (tid < SBINS) hist[tid] = 0u;
    if (tid == 0) s_bcnt = 0u;
    __syncthreads();

    uint32_t cc = cnt[row]; if (cc > MAXC) cc = MAXC;

    // load candidates, recompute m, histogram
    for (uint32_t i = tid; i < cc; i += TPB) {
        uint32_t col = cidx_g[row * (uint32_t)MAXC + i];
        uint32_t m = jax_bits(base + col) >> 9;
        uint32_t d = m - TM;
        cm[i] = d;
        cidx[i] = col;
        atomicAdd(&hist[d >> 11], 1u);
    }
    __syncthreads();

    // suffix scan over 256 bins (Hillis-Steele, 8 steps)
    uint32_t h = 0, S = 0;
    if (tid < SBINS) { h = hist[tid]; scanb[tid] = h; }
    __syncthreads();
    S = h;
    for (uint32_t off = 1; off < SBINS; off <<= 1) {
        uint32_t v = 0;
        if (tid < SBINS && tid + off < SBINS) v = scanb[tid + off];
        __syncthreads();
        if (tid < SBINS) { S += v; scanb[tid] = S; }
        __syncthreads();
    }
    if (tid < SBINS) {
        uint32_t above = S - h;            // candidates in bins strictly above mine
        if (above < KSEL && S >= KSEL) {   // exactly one thread
            s_bstar = tid;
            s_r = KSEL - above;            // how many to take from the boundary bin
        }
    }
    __syncthreads();

    const uint32_t bstar = s_bstar;
    const uint32_t r     = s_r;

    // gather boundary-bin keys (value-desc / index-asc total order, distinct)
    for (uint32_t i = tid; i < cc; i += TPB) {
        if ((cm[i] >> 11) == bstar) {
            uint32_t p = atomicAdd(&s_bcnt, 1u);
            if (p < MAXB) bkeys[p] = ((cm[i] & 2047u) << 17) | (131071u - cidx[i]);
        }
    }
    __syncthreads();

    uint32_t bc = s_bcnt; if (bc > MAXB) bc = MAXB;
    if (tid < bc) {
        uint32_t mykey = bkeys[tid];
        uint32_t rank = 0;
        for (uint32_t i = 0; i < bc; ++i) rank += (bkeys[i] > mykey) ? 1u : 0u;
        if (rank == r - 1) s_tkey = mykey;   // keys distinct -> exactly one writer
    }
    __syncthreads();

    const uint32_t tkey = s_tkey;

    // scatter zeros (exactly KSEL elements per row)
    for (uint32_t i = tid; i < cc; i += TPB) {
        uint32_t bin = cm[i] >> 11;
        bool z = (bin > bstar);
        if (bin == bstar) {
            uint32_t key = ((cm[i] & 2047u) << 17) | (131071u - cidx[i]);
            z = (key >= tkey);
        }
        if (z) out[base + cidx[i]] = 0.0f;
    }
}

extern "C" void kernel_launch(void* const* d_in, const int* in_sizes, int n_in,
                              void* d_out, int out_size, void* d_ws, size_t ws_size,
                              hipStream_t stream) {
    const float* in = (const float*)d_in[0];
    float* out = (float*)d_out;
    uint32_t* cnt    = (uint32_t*)d_ws;                 // 256 u32
    uint32_t* cidx_g = (uint32_t*)d_ws + NROWS;         // 256 * 5120 u32  (~5.25 MB total)

    hipLaunchKernelGGL(zero_counts, dim3(1), dim3(NROWS), 0, stream, cnt);
    hipLaunchKernelGGL(pass1_kernel, dim3(NROWS * 2), dim3(TPB), 0, stream, in, out, cnt, cidx_g);
    hipLaunchKernelGGL(select_kernel, dim3(NROWS), dim3(TPB), 0, stream, out, cnt, cidx_g);
}